// Round 1
// 1043.141 us; speedup vs baseline: 1.0466x; 1.0466x over previous
//
#include <hip/hip_runtime.h>
#include <stdint.h>
#include <stddef.h>

#define MDIM 4096
#define NDIM 16384
#define KDIM 4096

typedef __bf16 bf16;
typedef __bf16 bf16x8 __attribute__((ext_vector_type(8)));
typedef float  fx4    __attribute__((ext_vector_type(4)));
typedef int    ix4    __attribute__((ext_vector_type(4)));

#define AS1(p) ((const __attribute__((address_space(1))) void*)(p))
#define AS3(p) ((__attribute__((address_space(3))) void*)(p))

// ---------------- conversion kernels (16B loads, 16B stores, 8 elem/thread) ----------------
__global__ __launch_bounds__(256) void cvt_x_kernel(const fx4* __restrict__ x,
                                                    bf16x8* __restrict__ xb, int n8) {
    int i = blockIdx.x * 256 + threadIdx.x;
    if (i < n8) {
        fx4 v0 = x[2 * i];
        fx4 v1 = x[2 * i + 1];
        bf16x8 o;
        o[0] = (bf16)v0[0]; o[1] = (bf16)v0[1]; o[2] = (bf16)v0[2]; o[3] = (bf16)v0[3];
        o[4] = (bf16)v1[0]; o[5] = (bf16)v1[1]; o[6] = (bf16)v1[2]; o[7] = (bf16)v1[3];
        xb[i] = o;
    }
}

__global__ __launch_bounds__(256) void cvt_w_kernel(const ix4* __restrict__ q,
                                                    bf16x8* __restrict__ wb,
                                                    const float* __restrict__ zp_ptr, int n8) {
    float zp = *zp_ptr;
    int i = blockIdx.x * 256 + threadIdx.x;
    if (i < n8) {
        ix4 v0 = q[2 * i];
        ix4 v1 = q[2 * i + 1];
        bf16x8 o;
        o[0] = (bf16)((float)v0[0] - zp); o[1] = (bf16)((float)v0[1] - zp);
        o[2] = (bf16)((float)v0[2] - zp); o[3] = (bf16)((float)v0[3] - zp);
        o[4] = (bf16)((float)v1[0] - zp); o[5] = (bf16)((float)v1[1] - zp);
        o[6] = (bf16)((float)v1[2] - zp); o[7] = (bf16)((float)v1[3] - zp);
        wb[i] = o;
    }
}

// ---------------- main GEMM: C[M,N] = A[M,K] * B[N,K]^T, epilogue scale+bias ----------------
// 256x256 tile, BK=64 split into two 32-k halves, 512 threads = 8 waves (2M x 4N),
// per-wave 128x64 output via 8x4 MFMA 16x16x32 accumulators.
//
// Pipeline: 4-deep K-half ring buffer in LDS (2 tiles x 2 halves, 128 KiB total).
// Each phase: issue next-next K-half staging (4 global_load_lds), counted
// s_waitcnt vmcnt(8) (2 K-halves = 8 loads stay in flight across barriers -- never
// drained to 0 in the main loop), raw s_barrier, 12 ds_read_b128, setprio(1),
// 32 MFMA, setprio(0), s_barrier.  sched_barrier(0) pins each phase's load+MFMA
// region between the raw barriers so the compiler cannot hoist ds_reads above the
// deposit wait or sink them past the trailing barrier into the next phase's
// staging (WAR on the ring slot being rewritten).
//
// LDS swizzle (same scheme as the verified 128^2 kernel, 0 measured conflicts):
// each K-half panel is [256 rows][32 k] bf16, row = 64 B = 4 chunks of 16 B;
// stored chunk s of row r holds global chunk s ^ ((r>>1)&3), implemented by
// permuting the staging lane's global k-offset (global_load_lds deposits stay
// linear: wave-uniform base + lane*16).  Reads use chunk (fq ^ ((fr>>1)&3)) --
// every 16-lane group covers all 8 bank-quads exactly twice = free 2-way.
__global__ __launch_bounds__(512, 2) void gemm_kernel(const bf16* __restrict__ A,
                                                      const bf16* __restrict__ B,
                                                      const float* __restrict__ scale_ptr,
                                                      const float* __restrict__ bias,
                                                      float* __restrict__ C) {
    // [buf 0/1][kh 0/1][256*32 bf16] per operand: 2*2*8192 elems = 32 KiB*2 = 64 KiB each
    __shared__ bf16 As[2 * 2 * 8192];
    __shared__ bf16 Bs[2 * 2 * 8192];

    const int tid  = threadIdx.x;
    const int wave = tid >> 6;
    const int lane = tid & 63;

    // Bijective XCD-aware swizzle: 1024 blocks, 8 XCDs, 128 blocks/XCD chunk.
    // bn fastest inside a chunk -> each XCD keeps 2 A-panels hot while sweeping B.
    const int bid = blockIdx.x;
    const int swz = (bid & 7) * 128 + (bid >> 3);
    const int bm = swz >> 6;    // 0..15
    const int bn = swz & 63;    // 0..63

    // ---- staging geometry ----
    // Issue (wave, j): LDS bytes (wave*2+j)*1024 + lane*16 within a K-half panel
    //   -> row r = (wave*2+j)*16 + (lane>>2), stored chunk = lane&3.
    // Source global chunk = (lane&3) ^ ((r>>1)&3) = (lane&3) ^ ((lane>>3)&3).
    const int rowS   = wave * 32 + (lane >> 2);               // j=0 row; j=1 adds 16
    const int gChunk = (lane & 3) ^ ((lane >> 3) & 3);
    const bf16* aS0 = A + (size_t)(bm * 256 + rowS) * KDIM + gChunk * 8;
    const bf16* aS1 = aS0 + (size_t)16 * KDIM;
    const bf16* bS0 = B + (size_t)(bn * 256 + rowS) * KDIM + gChunk * 8;
    const bf16* bS1 = bS0 + (size_t)16 * KDIM;
    const int ldsW0 = wave * 1024;          // element offset of issue j=0 in a panel
    const int ldsW1 = wave * 1024 + 512;    // issue j=1

    // ---- fragment geometry ----
    const int wm = wave >> 2;               // 0..1  (M half)
    const int wn = wave & 3;                // 0..3  (N quarter)
    const int fr = lane & 15;
    const int fq = lane >> 4;
    const int sw = (fr >> 1) & 3;           // invariant under +16-row steps
    const int aOff = (wm * 128 + fr) * 32 + ((fq ^ sw) * 8);
    const int bOff = (wn * 64  + fr) * 32 + ((fq ^ sw) * 8);

    fx4 acc[8][4];
#pragma unroll
    for (int mi = 0; mi < 8; ++mi)
#pragma unroll
        for (int ni = 0; ni < 4; ++ni)
            acc[mi][ni] = fx4{0.f, 0.f, 0.f, 0.f};

// stage K-half kh of a tile (k byte-column kg) into ring slot (bufSel, kh): 4 loads
#define STAGE(bufSel, kh, kg) do {                                                        \
    const int _o = (bufSel) * 16384 + (kh) * 8192;                                        \
    __builtin_amdgcn_global_load_lds(AS1(aS0 + (kg)), AS3(As + _o + ldsW0), 16, 0, 0);    \
    __builtin_amdgcn_global_load_lds(AS1(aS1 + (kg)), AS3(As + _o + ldsW1), 16, 0, 0);    \
    __builtin_amdgcn_global_load_lds(AS1(bS0 + (kg)), AS3(Bs + _o + ldsW0), 16, 0, 0);    \
    __builtin_amdgcn_global_load_lds(AS1(bS1 + (kg)), AS3(Bs + _o + ldsW1), 16, 0, 0);    \
} while (0)

// read 12 fragments from ring slot (bufSel, kh) and fire 32 MFMAs
#define COMPUTE(bufSel, kh) do {                                                          \
    const bf16* _aB = As + (bufSel) * 16384 + (kh) * 8192 + aOff;                         \
    const bf16* _bB = Bs + (bufSel) * 16384 + (kh) * 8192 + bOff;                         \
    bf16x8 af[8], bfr[4];                                                                 \
    _Pragma("unroll")                                                                     \
    for (int mi = 0; mi < 8; ++mi) af[mi] = *(const bf16x8*)(_aB + mi * 512);             \
    _Pragma("unroll")                                                                     \
    for (int ni = 0; ni < 4; ++ni) bfr[ni] = *(const bf16x8*)(_bB + ni * 512);            \
    __builtin_amdgcn_s_setprio(1);                                                        \
    _Pragma("unroll")                                                                     \
    for (int mi = 0; mi < 8; ++mi)                                                        \
        _Pragma("unroll")                                                                 \
        for (int ni = 0; ni < 4; ++ni)                                                    \
            acc[mi][ni] = __builtin_amdgcn_mfma_f32_16x16x32_bf16(af[mi], bfr[ni],        \
                                                                  acc[mi][ni], 0, 0, 0); \
    __builtin_amdgcn_s_setprio(0);                                                        \
} while (0)

// one phase: stage (bufW, kh) of the tile 1 ahead, wait the K-half staged 2 phases ago,
// compute (bufR, kh) of the current tile.  vmcnt(8) = 2 K-halves (8 loads) in flight.
#define PHASE_S(bufR, kh, kgNext) do {                                                    \
    STAGE((bufR) ^ 1, kh, kgNext);                                                        \
    asm volatile("s_waitcnt vmcnt(8)" ::: "memory");                                      \
    __builtin_amdgcn_s_barrier();                                                         \
    __builtin_amdgcn_sched_barrier(0);                                                    \
    COMPUTE(bufR, kh);                                                                    \
    __builtin_amdgcn_sched_barrier(0);                                                    \
    __builtin_amdgcn_s_barrier();                                                         \
} while (0)

    // ---- prologue: stage tile 0 (both K-halves) into buf 0: 8 loads in flight ----
    STAGE(0, 0, 0);
    STAGE(0, 1, 32);

    // ---- main loop: tiles 0..62 compute, each staging tile t+1 ----
    // Unrolled by 2 so the ring-slot selectors are compile-time constants.
    for (int t = 0; t < 62; t += 2) {
        const int kg = t * 64;
        PHASE_S(0, 0, kg + 64);
        PHASE_S(0, 1, kg + 96);
        PHASE_S(1, 0, kg + 128);
        PHASE_S(1, 1, kg + 160);
    }
    {   // t = 62 (buf 0), stages tile 63 (k = 4032) into buf 1
        PHASE_S(0, 0, 4032);
        PHASE_S(0, 1, 4064);
    }
    // ---- peeled last tile t = 63 (buf 1), no staging; drain 4 then 0 ----
    asm volatile("s_waitcnt vmcnt(4)" ::: "memory");
    __builtin_amdgcn_s_barrier();
    __builtin_amdgcn_sched_barrier(0);
    COMPUTE(1, 0);
    __builtin_amdgcn_sched_barrier(0);
    __builtin_amdgcn_s_barrier();
    asm volatile("s_waitcnt vmcnt(0)" ::: "memory");
    __builtin_amdgcn_s_barrier();
    __builtin_amdgcn_sched_barrier(0);
    COMPUTE(1, 1);

#undef PHASE_S
#undef COMPUTE
#undef STAGE

    // Fence: keep scale/bias loads from being hoisted above (their outstanding
    // vmcnt would corrupt the counted waits in the loop).
    asm volatile("" ::: "memory");

    // ---- epilogue: C/D layout col = lane&15, row = (lane>>4)*4 + reg ----
    const float s = *scale_ptr;
    float bv[4];
#pragma unroll
    for (int ni = 0; ni < 4; ++ni)
        bv[ni] = bias[bn * 256 + wn * 64 + ni * 16 + fr];

    const int c0 = bn * 256 + wn * 64 + fr;
    const int r0 = bm * 256 + wm * 128 + fq * 4;
#pragma unroll
    for (int mi = 0; mi < 8; ++mi) {
#pragma unroll
        for (int i = 0; i < 4; ++i) {
            float* crow = C + (size_t)(r0 + mi * 16 + i) * NDIM + c0;
#pragma unroll
            for (int ni = 0; ni < 4; ++ni)
                crow[ni * 16] = s * acc[mi][ni][i] + bv[ni];
        }
    }
}

// ---------------- slow-but-correct fallback (only if ws_size is too small) ----------------
__global__ __launch_bounds__(256) void naive_kernel(const float* __restrict__ x,
                                                    const int* __restrict__ q,
                                                    const float* __restrict__ sp,
                                                    const float* __restrict__ zpp,
                                                    const float* __restrict__ bias,
                                                    float* __restrict__ out) {
    float s = *sp, zp = *zpp;
    size_t idx = (size_t)blockIdx.x * 256 + threadIdx.x;
    int m = (int)(idx / NDIM);
    int n = (int)(idx % NDIM);
    const fx4* xr = (const fx4*)(x + (size_t)m * KDIM);
    const ix4* qr = (const ix4*)(q + (size_t)n * KDIM);
    float acc = 0.f;
    for (int k = 0; k < KDIM / 4; ++k) {
        fx4 xv = xr[k];
        ix4 qv = qr[k];
        acc += xv[0] * ((float)qv[0] - zp) + xv[1] * ((float)qv[1] - zp)
             + xv[2] * ((float)qv[2] - zp) + xv[3] * ((float)qv[3] - zp);
    }
    out[idx] = s * acc + bias[n];
}

extern "C" void kernel_launch(void* const* d_in, const int* in_sizes, int n_in,
                              void* d_out, int out_size, void* d_ws, size_t ws_size,
                              hipStream_t stream) {
    const float* x     = (const float*)d_in[0];
    const int*   q     = (const int*)d_in[1];
    const float* scale = (const float*)d_in[2];
    const float* zp    = (const float*)d_in[3];
    const float* bias  = (const float*)d_in[4];
    float* out = (float*)d_out;

    const size_t need = ((size_t)MDIM * KDIM + (size_t)NDIM * KDIM) * sizeof(bf16); // 160 MiB
    if (ws_size >= need) {
        bf16* xb = (bf16*)d_ws;
        bf16* wb = xb + (size_t)MDIM * KDIM;

        const int nx8 = MDIM * KDIM / 8;   // 2,097,152
        const int nw8 = NDIM * KDIM / 8;   // 8,388,608
        cvt_x_kernel<<<nx8 / 256, 256, 0, stream>>>((const fx4*)x, (bf16x8*)xb, nx8);
        cvt_w_kernel<<<nw8 / 256, 256, 0, stream>>>((const ix4*)q, (bf16x8*)wb, zp, nw8);

        dim3 grid((NDIM / 256) * (MDIM / 256));   // 64 * 16 = 1024 blocks
        gemm_kernel<<<grid, 512, 0, stream>>>(xb, wb, scale, bias, out);
    } else {
        naive_kernel<<<((size_t)MDIM * NDIM) / 256, 256, 0, stream>>>(x, q, scale, zp, bias, out);
    }
}

// Round 2
// 1008.649 us; speedup vs baseline: 1.0824x; 1.0342x over previous
//
#include <hip/hip_runtime.h>
#include <stdint.h>
#include <stddef.h>

#define MDIM 4096
#define NDIM 16384
#define KDIM 4096

typedef __bf16 bf16;
typedef __bf16 bf16x8 __attribute__((ext_vector_type(8)));
typedef float  fx4    __attribute__((ext_vector_type(4)));
typedef int    ix4    __attribute__((ext_vector_type(4)));

#define AS1(p) ((const __attribute__((address_space(1))) void*)(p))
#define AS3(p) ((__attribute__((address_space(3))) void*)(p))

// ---------------- conversion kernels (16B loads, 16B stores, 8 elem/thread) ----------------
__global__ __launch_bounds__(256) void cvt_x_kernel(const fx4* __restrict__ x,
                                                    bf16x8* __restrict__ xb, int n8) {
    int i = blockIdx.x * 256 + threadIdx.x;
    if (i < n8) {
        fx4 v0 = x[2 * i];
        fx4 v1 = x[2 * i + 1];
        bf16x8 o;
        o[0] = (bf16)v0[0]; o[1] = (bf16)v0[1]; o[2] = (bf16)v0[2]; o[3] = (bf16)v0[3];
        o[4] = (bf16)v1[0]; o[5] = (bf16)v1[1]; o[6] = (bf16)v1[2]; o[7] = (bf16)v1[3];
        xb[i] = o;
    }
}

__global__ __launch_bounds__(256) void cvt_w_kernel(const ix4* __restrict__ q,
                                                    bf16x8* __restrict__ wb,
                                                    const float* __restrict__ zp_ptr, int n8) {
    float zp = *zp_ptr;
    int i = blockIdx.x * 256 + threadIdx.x;
    if (i < n8) {
        ix4 v0 = q[2 * i];
        ix4 v1 = q[2 * i + 1];
        bf16x8 o;
        o[0] = (bf16)((float)v0[0] - zp); o[1] = (bf16)((float)v0[1] - zp);
        o[2] = (bf16)((float)v0[2] - zp); o[3] = (bf16)((float)v0[3] - zp);
        o[4] = (bf16)((float)v1[0] - zp); o[5] = (bf16)((float)v1[1] - zp);
        o[6] = (bf16)((float)v1[2] - zp); o[7] = (bf16)((float)v1[3] - zp);
        wb[i] = o;
    }
}

// ---------------- main GEMM: C[M,N] = A[M,K] * B[N,K]^T, epilogue scale+bias ----------------
// 256x256 tile, 512 threads = 8 waves (2M x 4N), per-wave 128x64 via 8x4 MFMA 16x16x32.
//
// K pipeline at K-half (32) granularity, flat 4-slot ring per operand (4 x 16 KiB each,
// 128 KiB LDS total).  Phase p (template ordering: reads BEFORE the barrier):
//   ds_read 12 frags of K-half p from slot (p&3)        <- issued in previous interval
//   STAGE   K-half p+3 into slot ((p+3)&3)  (4 global_load_lds)
//   s_waitcnt vmcnt(8)     <- completes the stage issued at p-2 (data for phase p+1);
//                             2 K-halves stay in flight across barriers, never 0
//   s_barrier              <- makes that per-wave vmcnt a global guarantee
//   setprio(1); 32 MFMA from regs; setprio(0)
//   s_barrier              <- all waves' reads consumed (lgkm drained before MFMA) =>
//                             next phase's STAGE may overwrite slot (p&3)'s successor
// The read drain (~96 ds_read_b128/CU/phase) rides through the barrier and overlaps the
// MFMA interval via per-wave lgkm completion stagger -- this is the overlap the previous
// revision (reads inside the MFMA interval) was missing.
//
// Guarantee chain: reads(p) target the slot staged at p-3, covered by vmcnt(8)+barrier of
// phase p-1 (prologue vmcnt(8)+barrier for p=0).  Tail drains vmcnt 8 -> 4 -> 0.
//
// LDS swizzle (unchanged, 0 measured conflicts): panel row = 64 B = 4 chunks of 16 B;
// stored chunk s of row r holds global chunk s ^ ((r>>1)&3), via permuted staging lane
// global k-offset (deposits stay linear).  Reads use chunk fq ^ ((fr>>1)&3).
__global__ __launch_bounds__(512, 2) void gemm_kernel(const bf16* __restrict__ A,
                                                      const bf16* __restrict__ B,
                                                      const float* __restrict__ scale_ptr,
                                                      const float* __restrict__ bias,
                                                      float* __restrict__ C) {
    __shared__ bf16 As[4 * 8192];   // 4 K-half slots x [256 rows][32 k]
    __shared__ bf16 Bs[4 * 8192];

    const int tid  = threadIdx.x;
    const int wave = tid >> 6;
    const int lane = tid & 63;

    // Bijective XCD-aware swizzle: 1024 blocks, 8 XCDs, 128 blocks/XCD chunk.
    const int bid = blockIdx.x;
    const int swz = (bid & 7) * 128 + (bid >> 3);
    const int bm = swz >> 6;    // 0..15
    const int bn = swz & 63;    // 0..63

    // ---- staging geometry ----
    // Issue (wave, j): within a slot, LDS bytes (wave*2+j)*1024 + lane*16
    //   -> row r = wave*32 + j*16 + (lane>>2), stored chunk = lane&3.
    // Source global chunk = (lane&3) ^ ((r>>1)&3) = (lane&3) ^ ((lane>>3)&3).
    const int rowS   = wave * 32 + (lane >> 2);
    const int gChunk = (lane & 3) ^ ((lane >> 3) & 3);
    const bf16* aS0 = A + (size_t)(bm * 256 + rowS) * KDIM + gChunk * 8;
    const bf16* aS1 = aS0 + (size_t)16 * KDIM;
    const bf16* bS0 = B + (size_t)(bn * 256 + rowS) * KDIM + gChunk * 8;
    const bf16* bS1 = bS0 + (size_t)16 * KDIM;
    const int ldsW0 = wave * 1024;          // element offset of issue j=0 within a slot
    const int ldsW1 = wave * 1024 + 512;

    // ---- fragment geometry ----
    const int wm = wave >> 2;               // 0..1  (M half)
    const int wn = wave & 3;                // 0..3  (N quarter)
    const int fr = lane & 15;
    const int fq = lane >> 4;
    const int sw = (fr >> 1) & 3;
    const int aOff = (wm * 128 + fr) * 32 + ((fq ^ sw) * 8);
    const int bOff = (wn * 64  + fr) * 32 + ((fq ^ sw) * 8);

    fx4 acc[8][4];
#pragma unroll
    for (int mi = 0; mi < 8; ++mi)
#pragma unroll
        for (int ni = 0; ni < 4; ++ni)
            acc[mi][ni] = fx4{0.f, 0.f, 0.f, 0.f};

// stage K-half with element k-offset kg into ring slot slotW: 4 global_load_lds
#define STAGE(slotW, kg) do {                                                             \
    __builtin_amdgcn_global_load_lds(AS1(aS0 + (kg)), AS3(As + (slotW) * 8192 + ldsW0), 16, 0, 0); \
    __builtin_amdgcn_global_load_lds(AS1(aS1 + (kg)), AS3(As + (slotW) * 8192 + ldsW1), 16, 0, 0); \
    __builtin_amdgcn_global_load_lds(AS1(bS0 + (kg)), AS3(Bs + (slotW) * 8192 + ldsW0), 16, 0, 0); \
    __builtin_amdgcn_global_load_lds(AS1(bS1 + (kg)), AS3(Bs + (slotW) * 8192 + ldsW1), 16, 0, 0); \
} while (0)

// one phase: reads first, stage second, counted wait, barrier, MFMA, barrier.
#define PHASE_BODY(slotR, STAGE_STMT, WAIT_STMT) do {                                     \
    const bf16* _aB = As + (slotR) * 8192 + aOff;                                         \
    const bf16* _bB = Bs + (slotR) * 8192 + bOff;                                         \
    bf16x8 af[8], bfr[4];                                                                 \
    _Pragma("unroll")                                                                     \
    for (int mi = 0; mi < 8; ++mi) af[mi] = *(const bf16x8*)(_aB + mi * 512);             \
    _Pragma("unroll")                                                                     \
    for (int ni = 0; ni < 4; ++ni) bfr[ni] = *(const bf16x8*)(_bB + ni * 512);            \
    STAGE_STMT;                                                                           \
    WAIT_STMT;                                                                            \
    __builtin_amdgcn_sched_barrier(0);                                                    \
    __builtin_amdgcn_s_barrier();                                                         \
    __builtin_amdgcn_sched_barrier(0);                                                    \
    __builtin_amdgcn_s_setprio(1);                                                        \
    _Pragma("unroll")                                                                     \
    for (int mi = 0; mi < 8; ++mi)                                                        \
        _Pragma("unroll")                                                                 \
        for (int ni = 0; ni < 4; ++ni)                                                    \
            acc[mi][ni] = __builtin_amdgcn_mfma_f32_16x16x32_bf16(af[mi], bfr[ni],        \
                                                                  acc[mi][ni], 0, 0, 0); \
    __builtin_amdgcn_s_setprio(0);                                                        \
    __builtin_amdgcn_sched_barrier(0);                                                    \
    __builtin_amdgcn_s_barrier();                                                         \
} while (0)

#define VM8  asm volatile("s_waitcnt vmcnt(8)" ::: "memory")
#define VM4  asm volatile("s_waitcnt vmcnt(4)" ::: "memory")
#define VM0  asm volatile("s_waitcnt vmcnt(0)" ::: "memory")
#define PHASE_S(slotR, slotW, kg) PHASE_BODY(slotR, STAGE(slotW, kg), VM8)
#define PHASE_T(slotR, WAIT_STMT) PHASE_BODY(slotR, (void)0, WAIT_STMT)

    // ---- prologue: stage K-halves 0,1,2 into slots 0,1,2; guarantee kh0 ----
    STAGE(0, 0);
    STAGE(1, 32);
    STAGE(2, 64);
    VM8;                                   // 12 outstanding -> drains kh0's 4 loads
    __builtin_amdgcn_s_barrier();
    __builtin_amdgcn_sched_barrier(0);

    // ---- main loop: phases 0..123 (stage kh p+3), unrolled x4 for constant slots ----
    for (int p = 0; p < 124; p += 4) {
        const int kg = p * 32 + 96;        // = (p+3) * 32
        PHASE_S(0, 3, kg);
        PHASE_S(1, 0, kg + 32);
        PHASE_S(2, 1, kg + 64);
        PHASE_S(3, 2, kg + 96);
    }
    // phase 124: stages kh127 (last)
    PHASE_S(0, 3, 4064);
    // phases 125..127: no staging, drain 8 -> 4 -> 0
    PHASE_T(1, VM4);
    PHASE_T(2, VM0);
    PHASE_T(3, (void)0);

#undef PHASE_S
#undef PHASE_T
#undef PHASE_BODY
#undef STAGE
#undef VM8
#undef VM4
#undef VM0

    // Fence: keep scale/bias loads from being hoisted into the counted-vmcnt region.
    asm volatile("" ::: "memory");

    // ---- epilogue: C/D layout col = lane&15, row = (lane>>4)*4 + reg ----
    const float s = *scale_ptr;
    float bv[4];
#pragma unroll
    for (int ni = 0; ni < 4; ++ni)
        bv[ni] = bias[bn * 256 + wn * 64 + ni * 16 + fr];

    const int c0 = bn * 256 + wn * 64 + fr;
    const int r0 = bm * 256 + wm * 128 + fq * 4;
#pragma unroll
    for (int mi = 0; mi < 8; ++mi) {
#pragma unroll
        for (int i = 0; i < 4; ++i) {
            float* crow = C + (size_t)(r0 + mi * 16 + i) * NDIM + c0;
#pragma unroll
            for (int ni = 0; ni < 4; ++ni)
                crow[ni * 16] = s * acc[mi][ni][i] + bv[ni];
        }
    }
}

// ---------------- slow-but-correct fallback (only if ws_size is too small) ----------------
__global__ __launch_bounds__(256) void naive_kernel(const float* __restrict__ x,
                                                    const int* __restrict__ q,
                                                    const float* __restrict__ sp,
                                                    const float* __restrict__ zpp,
                                                    const float* __restrict__ bias,
                                                    float* __restrict__ out) {
    float s = *sp, zp = *zpp;
    size_t idx = (size_t)blockIdx.x * 256 + threadIdx.x;
    int m = (int)(idx / NDIM);
    int n = (int)(idx % NDIM);
    const fx4* xr = (const fx4*)(x + (size_t)m * KDIM);
    const ix4* qr = (const ix4*)(q + (size_t)n * KDIM);
    float acc = 0.f;
    for (int k = 0; k < KDIM / 4; ++k) {
        fx4 xv = xr[k];
        ix4 qv = qr[k];
        acc += xv[0] * ((float)qv[0] - zp) + xv[1] * ((float)qv[1] - zp)
             + xv[2] * ((float)qv[2] - zp) + xv[3] * ((float)qv[3] - zp);
    }
    out[idx] = s * acc + bias[n];
}

extern "C" void kernel_launch(void* const* d_in, const int* in_sizes, int n_in,
                              void* d_out, int out_size, void* d_ws, size_t ws_size,
                              hipStream_t stream) {
    const float* x     = (const float*)d_in[0];
    const int*   q     = (const int*)d_in[1];
    const float* scale = (const float*)d_in[2];
    const float* zp    = (const float*)d_in[3];
    const float* bias  = (const float*)d_in[4];
    float* out = (float*)d_out;

    const size_t need = ((size_t)MDIM * KDIM + (size_t)NDIM * KDIM) * sizeof(bf16); // 160 MiB
    if (ws_size >= need) {
        bf16* xb = (bf16*)d_ws;
        bf16* wb = xb + (size_t)MDIM * KDIM;

        const int nx8 = MDIM * KDIM / 8;   // 2,097,152
        const int nw8 = NDIM * KDIM / 8;   // 8,388,608
        cvt_x_kernel<<<nx8 / 256, 256, 0, stream>>>((const fx4*)x, (bf16x8*)xb, nx8);
        cvt_w_kernel<<<nw8 / 256, 256, 0, stream>>>((const ix4*)q, (bf16x8*)wb, zp, nw8);

        dim3 grid((NDIM / 256) * (MDIM / 256));   // 64 * 16 = 1024 blocks
        gemm_kernel<<<grid, 512, 0, stream>>>(xb, wb, scale, bias, out);
    } else {
        naive_kernel<<<((size_t)MDIM * NDIM) / 256, 256, 0, stream>>>(x, q, scale, zp, bias, out);
    }
}